// Round 13
// baseline (13289.691 us; speedup 1.0000x reference)
//
#include <hip/hip_runtime.h>
#include <math.h>

#define BB 32
#define TT 2048
#define FF 16
#define CC 17
#define HH 64

typedef float v2f __attribute__((ext_vector_type(2)));
typedef float v4f __attribute__((ext_vector_type(4)));
typedef unsigned v2u __attribute__((ext_vector_type(2)));
typedef unsigned v4u __attribute__((ext_vector_type(4)));
typedef _Float16 h2 __attribute__((ext_vector_type(2)));

__device__ __forceinline__ float rl(float v, int lane) {
    return __int_as_float(__builtin_amdgcn_readlane(__float_as_int(v), lane));
}
__device__ __forceinline__ unsigned rlu(unsigned v, int lane) {
    return (unsigned)__builtin_amdgcn_readlane((int)v, lane);
}
__device__ __forceinline__ float uf(float v) {
    return __int_as_float(__builtin_amdgcn_readfirstlane(__float_as_int(v)));
}
__device__ __forceinline__ float ftanh(float x) {
    float e = __builtin_amdgcn_exp2f(x * 2.88539008177792681472f); // exp(2x)
    return 1.0f - 2.0f * __builtin_amdgcn_rcpf(e + 1.0f);
}
__device__ __forceinline__ float fdot2u(unsigned a, unsigned b, float c) {
    return __builtin_amdgcn_fdot2(__builtin_bit_cast(h2, a),
                                  __builtin_bit_cast(h2, b), c, false);
}
// pack (a,b) to f16x2, scaled by 2^8 (weights); RN; init-time only
__device__ __forceinline__ unsigned packw(float a, float b) {
    h2 p; p.x = (_Float16)(a * 256.0f); p.y = (_Float16)(b * 256.0f);
    return __builtin_bit_cast(unsigned, p);
}
// LDS-only barrier: no vmcnt(0) drain.
__device__ __forceinline__ void bar_lds() {
    asm volatile("s_waitcnt lgkmcnt(0)\n\ts_barrier" ::: "memory");
}
#define PIN(v) asm volatile("" : "+v"(v))

// R13: wave0 computes the WHOLE hidden chain solo and in-register
// (h broadcast via readlane; weights streamed from LDS as ds_read_b64 at
// row-stride 34 u32 -> 2-way banks = free; loads independent of h -> latency
// hidden). No barrier, no cross-wave combine for the hidden chain (4 of the
// 5 latency rounds R3-R12 could not remove). ONE h-publish barrier; out layer
// broadcasts h via UNIFORM-ADDRESS b128 LDS reads (no readlane hazards);
// pgq combine keeps R12's transposed layout. 2 barriers/G total.
__attribute__((amdgpu_waves_per_eu(2, 2)))
__launch_bounds__(512)
__global__ void ncde_main(const float* __restrict__ x,
                          const float* __restrict__ wi1, const float* __restrict__ bi1,
                          const float* __restrict__ wi2, const float* __restrict__ bi2,
                          const float* __restrict__ w_in, const float* __restrict__ b_in,
                          const float* __restrict__ w_hid, const float* __restrict__ b_hid,
                          const float* __restrict__ w_out, const float* __restrict__ b_out,
                          float* __restrict__ zT)
{
    const int b   = blockIdx.x;
    const int tid = threadIdx.x;
    const int w   = tid >> 6;
    const int l   = tid & 63;

    __shared__ unsigned WLds[4 * 64 * 34];           // hidden W, f16x2 pairs, row l stride 34
    __shared__ __align__(16) unsigned hb16[32];      // h*2^-8 f16x2 pairs
    __shared__ float pgqt[64][20];                   // transposed (pg,a16) combine rows

    const int cs = w ^ ((l >> 3) & 7);               // swizzled column (order-invariant sum)

    // ---- stage hidden weights: WLds[L][l][j] = packw(W_L[2j][l], W_L[2j+1][l]) ----
    for (int i = tid; i < 4 * 64 * 32; i += 512) {
        int L = i >> 11, r = i & 2047, col = r >> 5, j = r & 31;
        float wa, wb;
        if (L == 0) { wa = w_in[(2 * j) * HH + col];     wb = w_in[(2 * j + 1) * HH + col]; }
        else { wa = w_hid[((L - 1) * HH + 2 * j) * HH + col];
               wb = w_hid[((L - 1) * HH + 2 * j + 1) * HH + col]; }
        WLds[L * (64 * 34) + col * 34 + j] = packw(wa, wb);
    }

    float bh[4] = { b_in[l], b_hid[l], b_hid[HH + l], b_hid[2 * HH + l] };  // wave0 use

    // ---- out-layer weights (cols c0,c1 per wave + c16 k-slice), packed f16*2^8 ----
    const int c0 = 2 * w, c1 = 2 * w + 1;
    unsigned wo0p[32], wo1p[32], w16p[4];
    #pragma unroll
    for (int j = 0; j < 32; ++j) {
        wo0p[j] = packw(w_out[(2 * j) * (CC * HH) + l * CC + c0],
                        w_out[(2 * j + 1) * (CC * HH) + l * CC + c0]);
        wo1p[j] = packw(w_out[(2 * j) * (CC * HH) + l * CC + c1],
                        w_out[(2 * j + 1) * (CC * HH) + l * CC + c1]);
    }
    #pragma unroll
    for (int jj = 0; jj < 4; ++jj)
        w16p[jj] = packw(w_out[(8 * w + 2 * jj) * (CC * HH) + l * CC + 16],
                         w_out[(8 * w + 2 * jj + 1) * (CC * HH) + l * CC + 16]);
    float bo0  = b_out[l * CC + c0];
    float bo1  = b_out[l * CC + c1];
    float bo16 = (w == 0) ? b_out[l * CC + 16] : 0.0f;   // folded into wave0 partial

    #pragma unroll
    for (int j = 0; j < 32; ++j) { PIN(wo0p[j]); PIN(wo1p[j]); }
    #pragma unroll
    for (int jj = 0; jj < 4; ++jj) PIN(w16p[jj]);
    PIN(bo0); PIN(bo1); PIN(bo16);

    // ---- z0 = relu(xa0 @ wi1 + bi1) @ wi2 + bi2 (f32, once) ----
    float z;
    {
        float h0 = bi1[l];
        #pragma unroll
        for (int c = 1; c < CC; ++c)
            h0 = fmaf(x[(size_t)b * TT * FF + (c - 1)], wi1[c * HH + l], h0);
        h0 = fmaxf(h0, 0.0f);
        z = bi2[l];
        #pragma unroll
        for (int k = 0; k < 64; ++k)
            z = fmaf(rl(h0, k), wi2[k * HH + l], z);
    }
    if (w == 7) zT[(size_t)b * TT * HH + l] = z;
    __syncthreads();   // WLds staged

    // pack v*2^-8 into f16x2; lane l ends holding pair floor(l/2)
    auto packb = [&](float v) -> unsigned {
        float hs = v * 0.00390625f;
        float pr = __shfl_xor(hs, 1);
        float a  = (l & 1) ? pr : hs;
        float bb = (l & 1) ? hs : pr;
        return __builtin_bit_cast(unsigned, __builtin_amdgcn_cvt_pkrtz(a, bb));
    };

    // ---- g(zin, xd) ----
    auto G = [&](float zin, float xd0, float xd1, float xd16) -> float {
        if (w == 0) {
            // solo hidden chain, fully in-register
            float cur = zin;
            #pragma unroll
            for (int L = 0; L < 4; ++L) {
                const unsigned* WL = &WLds[L * (64 * 34) + l * 34];
                unsigned hp = packb(cur);
                v2u wr[16];
                #pragma unroll
                for (int r = 0; r < 4; ++r)
                    wr[r] = *reinterpret_cast<const v2u*>(&WL[2 * r]);
                float a0 = bh[L], a1 = 0.f, a2 = 0.f, a3 = 0.f;
                #pragma unroll
                for (int r = 0; r < 16; ++r) {
                    if (r + 4 < 16)
                        wr[r + 4] = *reinterpret_cast<const v2u*>(&WL[2 * (r + 4)]);
                    unsigned sx = rlu(hp, 4 * r);        // pair 2r   (lane 4r)
                    unsigned sy = rlu(hp, 4 * r + 2);    // pair 2r+1 (lane 4r+2)
                    if (r & 1) { a2 = fdot2u(sx, wr[r].x, a2); a3 = fdot2u(sy, wr[r].y, a3); }
                    else       { a0 = fdot2u(sx, wr[r].x, a0); a1 = fdot2u(sy, wr[r].y, a1); }
                }
                cur = fmaxf((a0 + a1) + (a2 + a3), 0.0f);
            }
            // publish h*2^-8 pairs (even lanes own pair l/2)
            unsigned hp = packb(cur);
            if ((l & 1) == 0) hb16[l >> 1] = hp;
        }
        bar_lds();   // barrier #1: h published

        // out layer: h via uniform-address b128 broadcasts (no readlane)
        float u0a = 0.f, u0b = 0.f, u0c = 0.f, u0d = 0.f;
        float u1a = 0.f, u1b = 0.f, u1c = 0.f, u1d = 0.f;
        #pragma unroll
        for (int j = 0; j < 8; ++j) {
            v4u q = *reinterpret_cast<const v4u*>(&hb16[4 * j]);
            u0a = fdot2u(q.x, wo0p[4 * j + 0], u0a);
            u0b = fdot2u(q.y, wo0p[4 * j + 1], u0b);
            u0c = fdot2u(q.z, wo0p[4 * j + 2], u0c);
            u0d = fdot2u(q.w, wo0p[4 * j + 3], u0d);
            u1a = fdot2u(q.x, wo1p[4 * j + 0], u1a);
            u1b = fdot2u(q.y, wo1p[4 * j + 1], u1b);
            u1c = fdot2u(q.z, wo1p[4 * j + 2], u1c);
            u1d = fdot2u(q.w, wo1p[4 * j + 3], u1d);
        }
        v4u qc = *reinterpret_cast<const v4u*>(&hb16[4 * w]);   // this wave's c16 slice
        float a16a = fdot2u(qc.x, w16p[0], fdot2u(qc.z, w16p[2], bo16));
        float a16b = fdot2u(qc.y, w16p[1], fdot2u(qc.w, w16p[3], 0.0f));

        float u0 = ((u0a + u0b) + (u0c + u0d)) + bo0;
        float u1 = ((u1a + u1b) + (u1c + u1d)) + bo1;
        float pg = ftanh(u0) * xd0 + ftanh(u1) * xd1;
        *reinterpret_cast<v2f*>(&pgqt[l][2 * cs]) = (v2f){ pg, a16a + a16b };
        bar_lds();   // barrier #2: partials published
        const float* prow = &pgqt[l][0];
        v4f r0 = *reinterpret_cast<const v4f*>(prow);
        v4f r1 = *reinterpret_cast<const v4f*>(prow + 4);
        v4f r2 = *reinterpret_cast<const v4f*>(prow + 8);
        v4f r3 = *reinterpret_cast<const v4f*>(prow + 12);
        float pgs  = ((r0.x + r0.z) + (r1.x + r1.z)) + ((r2.x + r2.z) + (r3.x + r3.z));
        float a16s = ((r0.y + r0.w) + (r1.y + r1.w)) + ((r2.y + r2.w) + (r3.y + r3.w));
        return fmaf(ftanh(a16s), xd16, pgs);
    };

    // ---- time scan (uniform x scalars in SGPRs) ----
    const float* xb = x + (size_t)b * TT * FF;
    const bool hasc0 = (w != 0);
    const int  f0 = 2 * w - 1;
    const int  f1 = 2 * w;
    float xp0  = hasc0 ? uf(xb[f0]) : 0.0f;
    float xp1  = uf(xb[f1]);
    float xp16 = uf(xb[15]);
    float xn0  = hasc0 ? uf(xb[FF + f0]) : 0.0f;
    float xn1  = uf(xb[FF + f1]);
    float xn16 = uf(xb[FF + 15]);
    float dc0  = hasc0 ? (xn0 - xp0) : 1.0f;
    float dc1  = xn1 - xp1;
    float dc16 = xn16 - xp16;
    float dp0 = dc0, dp1 = dc1, dp16 = dc16;
    xp0 = xn0; xp1 = xn1; xp16 = xn16;

    #pragma unroll 1
    for (int t = 0; t < TT - 1; ++t) {
        const float f43 = 4.0f / 3.0f;
        float x20  = dp0  + f43 * (dc0  - dp0);
        float x21  = dp1  + f43 * (dc1  - dp1);
        float x216 = dp16 + f43 * (dc16 - dp16);

        int tn = (t + 2 < TT) ? (t + 2) : (TT - 1);
        float yn0  = hasc0 ? uf(xb[tn * FF + f0]) : 0.0f;
        float yn1  = uf(xb[tn * FF + f1]);
        float yn16 = uf(xb[tn * FF + 15]);

        float k1 = G(z, dp0, dp1, dp16);
        float k2 = G(z + k1 * (1.0f / 3.0f), dc0, dc1, dc16);
        float k3 = G(z + (k2 - k1 * (1.0f / 3.0f)), x20, x21, x216);
        float k4 = G(z + (k1 - k2 + k3), dc0, dc1, dc16);
        z = z + 0.125f * (k1 + 3.0f * (k2 + k3) + k4);

        if (w == 7) zT[((size_t)b * TT + t + 1) * HH + l] = z;

        dp0 = dc0; dp1 = dc1; dp16 = dc16;
        dc0 = hasc0 ? (yn0 - xp0) : 1.0f;
        dc1 = yn1 - xp1;
        dc16 = yn16 - xp16;
        xp0 = yn0; xp1 = yn1; xp16 = yn16;
    }
}

// out = gelu_exact(zT) @ w_proj + b_proj ; mask = 0
__global__ void ncde_proj(const float* __restrict__ zT,
                          const float* __restrict__ w_proj, const float* __restrict__ b_proj,
                          float* __restrict__ out, float* __restrict__ mask)
{
    __shared__ float gz[16][64];
    const int blk = blockIdx.x;
    const int tid = threadIdx.x;
    const int r16 = tid >> 4, f = tid & 15;
    const int row0 = blk * 16;

    #pragma unroll
    for (int i = 0; i < 4; ++i) {
        int idx = tid + i * 256;
        int r = idx >> 6, k = idx & 63;
        float zv = zT[(size_t)(row0 + r) * HH + k];
        gz[r][k] = 0.5f * zv * (1.0f + erff(zv * 0.70710678118654752f));
    }
    __syncthreads();

    float acc = b_proj[f];
    #pragma unroll
    for (int k = 0; k < 64; ++k)
        acc = fmaf(gz[r16][k], w_proj[k * FF + f], acc);
    out[(size_t)(row0 + r16) * FF + f] = acc;
    if (f == 0) mask[row0 + r16] = 0.0f;
}

extern "C" void kernel_launch(void* const* d_in, const int* in_sizes, int n_in,
                              void* d_out, int out_size, void* d_ws, size_t ws_size,
                              hipStream_t stream)
{
    (void)in_sizes; (void)n_in; (void)d_ws; (void)ws_size; (void)out_size;
    const float* x      = (const float*)d_in[0];
    const float* wi1    = (const float*)d_in[1];
    const float* bi1    = (const float*)d_in[2];
    const float* wi2    = (const float*)d_in[3];
    const float* bi2    = (const float*)d_in[4];
    const float* w_in   = (const float*)d_in[5];
    const float* b_in   = (const float*)d_in[6];
    const float* w_hid  = (const float*)d_in[7];
    const float* b_hid  = (const float*)d_in[8];
    const float* w_out  = (const float*)d_in[9];
    const float* b_out  = (const float*)d_in[10];
    const float* w_proj = (const float*)d_in[11];
    const float* b_proj = (const float*)d_in[12];

    float* zT   = (float*)d_out;                       // B*T*H
    float* outp = zT + (size_t)BB * TT * HH;           // B*T*F
    float* mask = outp + (size_t)BB * TT * FF;         // B*T

    ncde_main<<<dim3(BB), dim3(512), 0, stream>>>(
        x, wi1, bi1, wi2, bi2, w_in, b_in, w_hid, b_hid, w_out, b_out, zT);
    ncde_proj<<<dim3((BB * TT) / 16), dim3(256), 0, stream>>>(
        zT, w_proj, b_proj, outp, mask);
}

// Round 14
// 12598.177 us; speedup vs baseline: 1.0549x; 1.0549x over previous
//
#include <hip/hip_runtime.h>
#include <math.h>

#define BB 32
#define TT 2048
#define FF 16
#define CC 17
#define HH 64

typedef float v2f __attribute__((ext_vector_type(2)));
typedef float v4f __attribute__((ext_vector_type(4)));
typedef unsigned v4u __attribute__((ext_vector_type(4)));
typedef _Float16 h2 __attribute__((ext_vector_type(2)));

__device__ __forceinline__ float rl(float v, int lane) {
    return __int_as_float(__builtin_amdgcn_readlane(__float_as_int(v), lane));
}
__device__ __forceinline__ unsigned rlu(unsigned v, int lane) {
    return (unsigned)__builtin_amdgcn_readlane((int)v, lane);
}
__device__ __forceinline__ float uf(float v) {
    return __int_as_float(__builtin_amdgcn_readfirstlane(__float_as_int(v)));
}
__device__ __forceinline__ float ftanh(float x) {
    float e = __builtin_amdgcn_exp2f(x * 2.88539008177792681472f); // exp(2x)
    return 1.0f - 2.0f * __builtin_amdgcn_rcpf(e + 1.0f);
}
__device__ __forceinline__ float fdot2u(unsigned a, unsigned b, float c) {
    return __builtin_amdgcn_fdot2(__builtin_bit_cast(h2, a),
                                  __builtin_bit_cast(h2, b), c, false);
}
// pack (a,b) to f16x2, scaled by 2^8 (weights); RN; init-time only
__device__ __forceinline__ unsigned packw(float a, float b) {
    h2 p; p.x = (_Float16)(a * 256.0f); p.y = (_Float16)(b * 256.0f);
    return __builtin_bit_cast(unsigned, p);
}
// LDS-only barrier: no vmcnt(0) drain.
__device__ __forceinline__ void bar_lds() {
    asm volatile("s_waitcnt lgkmcnt(0)\n\ts_barrier" ::: "memory");
}
#define PIN(v) asm volatile("" : "+v"(v))

// R12 (best: 12.86ms) with the out layer DE-HAZARDED: the 36 v_readlane
// broadcasts (SGPR-write->VALU-read wait-state chains, est ~700cy/G) are
// replaced by a per-wave PRIVATE LDS copy of the packed h pairs:
//   1 predicated ds_write (wave-internal ordering, NO barrier added)
//   + 9 uniform-address ds_read_b128 broadcasts.
// Hidden layers keep their 16 readlanes (short chains). Barriers stay 5/G.
__attribute__((amdgpu_waves_per_eu(2, 2)))
__launch_bounds__(512)
__global__ void ncde_main(const float* __restrict__ x,
                          const float* __restrict__ wi1, const float* __restrict__ bi1,
                          const float* __restrict__ wi2, const float* __restrict__ bi2,
                          const float* __restrict__ w_in, const float* __restrict__ b_in,
                          const float* __restrict__ w_hid, const float* __restrict__ b_hid,
                          const float* __restrict__ w_out, const float* __restrict__ b_out,
                          float* __restrict__ zT)
{
    const int b   = blockIdx.x;
    const int tid = threadIdx.x;
    const int w   = tid >> 6;
    const int l   = tid & 63;

    __shared__ float pht[4][64][12];                 // [layer][h-row][wave-col + pad]
    __shared__ float pgqt[64][20];                   // [h-row][(pg,a16) x 8 cols + pad]
    __shared__ __align__(16) unsigned hbw[8][32];    // per-wave private packed h pairs

    const int cs = w ^ ((l >> 3) & 7);   // swizzled column (order-invariant sum)

    // ---- hidden weights: wave w owns k-slice [8w,8w+8), packed 4 u32/layer ----
    unsigned whp[4][4];
    #pragma unroll
    for (int kk = 0; kk < 4; ++kk) {
        int k = 8 * w + 2 * kk;
        whp[0][kk] = packw(w_in[k * HH + l],               w_in[(k + 1) * HH + l]);
        whp[1][kk] = packw(w_hid[(0 * HH + k) * HH + l],   w_hid[(0 * HH + k + 1) * HH + l]);
        whp[2][kk] = packw(w_hid[(1 * HH + k) * HH + l],   w_hid[(1 * HH + k + 1) * HH + l]);
        whp[3][kk] = packw(w_hid[(2 * HH + k) * HH + l],   w_hid[(2 * HH + k + 1) * HH + l]);
    }
    float bfold[4];
    bfold[0] = (w == 0) ? b_in[l] : 0.0f;
    bfold[1] = (w == 0) ? b_hid[0 * HH + l] : 0.0f;
    bfold[2] = (w == 0) ? b_hid[1 * HH + l] : 0.0f;
    bfold[3] = (w == 0) ? b_hid[2 * HH + l] : 0.0f;

    // ---- out-layer weights (cols c0,c1 per wave + c16 k-slice), packed ----
    const int c0 = 2 * w, c1 = 2 * w + 1;
    unsigned wo0p[32], wo1p[32], w16p[4];
    #pragma unroll
    for (int j = 0; j < 32; ++j) {
        wo0p[j] = packw(w_out[(2 * j) * (CC * HH) + l * CC + c0],
                        w_out[(2 * j + 1) * (CC * HH) + l * CC + c0]);
        wo1p[j] = packw(w_out[(2 * j) * (CC * HH) + l * CC + c1],
                        w_out[(2 * j + 1) * (CC * HH) + l * CC + c1]);
    }
    #pragma unroll
    for (int jj = 0; jj < 4; ++jj)
        w16p[jj] = packw(w_out[(8 * w + 2 * jj) * (CC * HH) + l * CC + 16],
                         w_out[(8 * w + 2 * jj + 1) * (CC * HH) + l * CC + 16]);
    float bo0  = b_out[l * CC + c0];
    float bo1  = b_out[l * CC + c1];
    float bo16 = (w == 0) ? b_out[l * CC + 16] : 0.0f;   // folded into wave0 partial

    #pragma unroll
    for (int j = 0; j < 32; ++j) { PIN(wo0p[j]); PIN(wo1p[j]); }
    #pragma unroll
    for (int jj = 0; jj < 4; ++jj) PIN(w16p[jj]);
    #pragma unroll
    for (int lay = 0; lay < 4; ++lay) {
        PIN(whp[lay][0]); PIN(whp[lay][1]); PIN(whp[lay][2]); PIN(whp[lay][3]);
    }
    PIN(bo0); PIN(bo1); PIN(bo16);

    // ---- z0 = relu(xa0 @ wi1 + bi1) @ wi2 + bi2 (f32, once) ----
    float z;
    {
        float h0 = bi1[l];
        #pragma unroll
        for (int c = 1; c < CC; ++c)
            h0 = fmaf(x[(size_t)b * TT * FF + (c - 1)], wi1[c * HH + l], h0);
        h0 = fmaxf(h0, 0.0f);
        z = bi2[l];
        #pragma unroll
        for (int k = 0; k < 64; ++k)
            z = fmaf(rl(h0, k), wi2[k * HH + l], z);
    }
    if (w == 0) zT[(size_t)b * TT * HH + l] = z;

    // pack v*2^-8 into f16x2; every lane ends holding pair (v[2j],v[2j+1]), j=l>>1
    auto packb = [&](float v) -> unsigned {
        float hs = v * 0.00390625f;
        float pr = __shfl_xor(hs, 1);
        float a  = (l & 1) ? pr : hs;
        float bb = (l & 1) ? hs : pr;
        return __builtin_bit_cast(unsigned, __builtin_amdgcn_cvt_pkrtz(a, bb));
    };

    // ---- g(zin, xd) ----
    auto G = [&](float zin, float xd0, float xd1, float xd16) -> float {
        float cur = zin;
        #pragma unroll
        for (int L = 0; L < 4; ++L) {
            unsigned hp = packb(cur);
            float a0 = bfold[L], a1 = 0.0f;
            a0 = fdot2u(rlu(hp, 8 * w + 0), whp[L][0], a0);
            a1 = fdot2u(rlu(hp, 8 * w + 2), whp[L][1], a1);
            a0 = fdot2u(rlu(hp, 8 * w + 4), whp[L][2], a0);
            a1 = fdot2u(rlu(hp, 8 * w + 6), whp[L][3], a1);
            pht[L][l][cs] = a0 + a1;
            bar_lds();
            const float* row = &pht[L][l][0];
            v4f q0 = *reinterpret_cast<const v4f*>(row);       // cols 0..3 (any order)
            v4f q1 = *reinterpret_cast<const v4f*>(row + 4);   // cols 4..7
            float hsum = ((q0.x + q0.y) + (q0.z + q0.w)) + ((q1.x + q1.y) + (q1.z + q1.w));
            cur = fmaxf(hsum, 0.0f);
        }
        // out layer: publish packed h to THIS WAVE's private LDS row (no barrier
        // needed -- wave-internal ds ordering), then uniform-address b128 broadcasts.
        unsigned hp = packb(cur);
        if ((l & 1) == 0) hbw[w][l >> 1] = hp;
        float u0a = 0.f, u0b = 0.f, u0c = 0.f, u0d = 0.f;
        float u1a = 0.f, u1b = 0.f, u1c = 0.f, u1d = 0.f;
        #pragma unroll
        for (int j = 0; j < 8; ++j) {
            v4u q = *reinterpret_cast<const v4u*>(&hbw[w][4 * j]);
            u0a = fdot2u(q.x, wo0p[4 * j + 0], u0a);
            u0b = fdot2u(q.y, wo0p[4 * j + 1], u0b);
            u0c = fdot2u(q.z, wo0p[4 * j + 2], u0c);
            u0d = fdot2u(q.w, wo0p[4 * j + 3], u0d);
            u1a = fdot2u(q.x, wo1p[4 * j + 0], u1a);
            u1b = fdot2u(q.y, wo1p[4 * j + 1], u1b);
            u1c = fdot2u(q.z, wo1p[4 * j + 2], u1c);
            u1d = fdot2u(q.w, wo1p[4 * j + 3], u1d);
        }
        v4u qc = *reinterpret_cast<const v4u*>(&hbw[w][4 * w]);   // c16 k-slice pairs
        float a16a = fdot2u(qc.x, w16p[0], fdot2u(qc.z, w16p[2], bo16));
        float a16b = fdot2u(qc.y, w16p[1], fdot2u(qc.w, w16p[3], 0.0f));

        float u0 = ((u0a + u0b) + (u0c + u0d)) + bo0;
        float u1 = ((u1a + u1b) + (u1c + u1d)) + bo1;
        float pg = ftanh(u0) * xd0 + ftanh(u1) * xd1;
        *reinterpret_cast<v2f*>(&pgqt[l][2 * cs]) = (v2f){ pg, a16a + a16b };
        bar_lds();
        const float* prow = &pgqt[l][0];
        v4f r0 = *reinterpret_cast<const v4f*>(prow);
        v4f r1 = *reinterpret_cast<const v4f*>(prow + 4);
        v4f r2 = *reinterpret_cast<const v4f*>(prow + 8);
        v4f r3 = *reinterpret_cast<const v4f*>(prow + 12);
        float pgs  = ((r0.x + r0.z) + (r1.x + r1.z)) + ((r2.x + r2.z) + (r3.x + r3.z));
        float a16s = ((r0.y + r0.w) + (r1.y + r1.w)) + ((r2.y + r2.w) + (r3.y + r3.w));
        return fmaf(ftanh(a16s), xd16, pgs);
    };

    // ---- time scan (uniform x scalars in SGPRs) ----
    const float* xb = x + (size_t)b * TT * FF;
    const bool hasc0 = (w != 0);
    const int  f0 = 2 * w - 1;
    const int  f1 = 2 * w;
    float xp0  = hasc0 ? uf(xb[f0]) : 0.0f;
    float xp1  = uf(xb[f1]);
    float xp16 = uf(xb[15]);
    float xn0  = hasc0 ? uf(xb[FF + f0]) : 0.0f;
    float xn1  = uf(xb[FF + f1]);
    float xn16 = uf(xb[FF + 15]);
    float dc0  = hasc0 ? (xn0 - xp0) : 1.0f;
    float dc1  = xn1 - xp1;
    float dc16 = xn16 - xp16;
    float dp0 = dc0, dp1 = dc1, dp16 = dc16;
    xp0 = xn0; xp1 = xn1; xp16 = xn16;

    #pragma unroll 1
    for (int t = 0; t < TT - 1; ++t) {
        const float f43 = 4.0f / 3.0f;
        float x20  = dp0  + f43 * (dc0  - dp0);
        float x21  = dp1  + f43 * (dc1  - dp1);
        float x216 = dp16 + f43 * (dc16 - dp16);

        int tn = (t + 2 < TT) ? (t + 2) : (TT - 1);
        float yn0  = hasc0 ? uf(xb[tn * FF + f0]) : 0.0f;
        float yn1  = uf(xb[tn * FF + f1]);
        float yn16 = uf(xb[tn * FF + 15]);

        float k1 = G(z, dp0, dp1, dp16);
        float k2 = G(z + k1 * (1.0f / 3.0f), dc0, dc1, dc16);
        float k3 = G(z + (k2 - k1 * (1.0f / 3.0f)), x20, x21, x216);
        float k4 = G(z + (k1 - k2 + k3), dc0, dc1, dc16);
        z = z + 0.125f * (k1 + 3.0f * (k2 + k3) + k4);

        if (w == 0) zT[((size_t)b * TT + t + 1) * HH + l] = z;

        dp0 = dc0; dp1 = dc1; dp16 = dc16;
        dc0 = hasc0 ? (yn0 - xp0) : 1.0f;
        dc1 = yn1 - xp1;
        dc16 = yn16 - xp16;
        xp0 = yn0; xp1 = yn1; xp16 = yn16;
    }
}

// out = gelu_exact(zT) @ w_proj + b_proj ; mask = 0
__global__ void ncde_proj(const float* __restrict__ zT,
                          const float* __restrict__ w_proj, const float* __restrict__ b_proj,
                          float* __restrict__ out, float* __restrict__ mask)
{
    __shared__ float gz[16][64];
    const int blk = blockIdx.x;
    const int tid = threadIdx.x;
    const int r16 = tid >> 4, f = tid & 15;
    const int row0 = blk * 16;

    #pragma unroll
    for (int i = 0; i < 4; ++i) {
        int idx = tid + i * 256;
        int r = idx >> 6, k = idx & 63;
        float zv = zT[(size_t)(row0 + r) * HH + k];
        gz[r][k] = 0.5f * zv * (1.0f + erff(zv * 0.70710678118654752f));
    }
    __syncthreads();

    float acc = b_proj[f];
    #pragma unroll
    for (int k = 0; k < 64; ++k)
        acc = fmaf(gz[r16][k], w_proj[k * FF + f], acc);
    out[(size_t)(row0 + r16) * FF + f] = acc;
    if (f == 0) mask[row0 + r16] = 0.0f;
}

extern "C" void kernel_launch(void* const* d_in, const int* in_sizes, int n_in,
                              void* d_out, int out_size, void* d_ws, size_t ws_size,
                              hipStream_t stream)
{
    (void)in_sizes; (void)n_in; (void)d_ws; (void)ws_size; (void)out_size;
    const float* x      = (const float*)d_in[0];
    const float* wi1    = (const float*)d_in[1];
    const float* bi1    = (const float*)d_in[2];
    const float* wi2    = (const float*)d_in[3];
    const float* bi2    = (const float*)d_in[4];
    const float* w_in   = (const float*)d_in[5];
    const float* b_in   = (const float*)d_in[6];
    const float* w_hid  = (const float*)d_in[7];
    const float* b_hid  = (const float*)d_in[8];
    const float* w_out  = (const float*)d_in[9];
    const float* b_out  = (const float*)d_in[10];
    const float* w_proj = (const float*)d_in[11];
    const float* b_proj = (const float*)d_in[12];

    float* zT   = (float*)d_out;                       // B*T*H
    float* outp = zT + (size_t)BB * TT * HH;           // B*T*F
    float* mask = outp + (size_t)BB * TT * FF;         // B*T

    ncde_main<<<dim3(BB), dim3(512), 0, stream>>>(
        x, wi1, bi1, wi2, bi2, w_in, b_in, w_hid, b_hid, w_out, b_out, zT);
    ncde_proj<<<dim3((BB * TT) / 16), dim3(256), 0, stream>>>(
        zT, w_proj, b_proj, outp, mask);
}